// Round 1
// baseline (606.390 us; speedup 1.0000x reference)
//
#include <hip/hip_runtime.h>

#define B_  2
#define S_  1024
#define D_  4096
#define H_  32
#define HD_ 128
#define T_  (B_*S_)   // 2048 tokens

typedef int   i32x4 __attribute__((ext_vector_type(4)));
typedef float f32x4 __attribute__((ext_vector_type(4)));

__device__ __forceinline__ unsigned short f2bf(float f) {
  unsigned int u = __float_as_uint(f);
  u += 0x7fffu + ((u >> 16) & 1u);     // round-to-nearest-even
  return (unsigned short)(u >> 16);
}
__device__ __forceinline__ float bf2f(unsigned short h) {
  return __uint_as_float(((unsigned int)h) << 16);
}
__device__ __forceinline__ void gload_lds16(const void* g, void* l) {
  __builtin_amdgcn_global_load_lds(
      (const __attribute__((address_space(1))) unsigned int*)g,
      (__attribute__((address_space(3))) unsigned int*)l, 16, 0, 0);
}
// D = A*B + C, 16x16x32 bf16. Inline asm avoids builtin vector-type ambiguity.
__device__ __forceinline__ void mfma16(i32x4 a, i32x4 b, f32x4& c) {
  asm("v_mfma_f32_16x16x32_bf16 %0, %1, %2, %0" : "+v"(c) : "v"(a), "v"(b));
}

// ---------------- f32 -> bf16 convert (vectorized, 8 elem/thread) ----------
__global__ __launch_bounds__(256) void cvt_bf16(const float* __restrict__ in,
                                                unsigned short* __restrict__ out,
                                                int n8) {
  int i = blockIdx.x * 256 + threadIdx.x;
  if (i >= n8) return;
  const float4* p = (const float4*)in + (size_t)i * 2;
  float4 a = p[0], b = p[1];
  unsigned short us[8] = {f2bf(a.x), f2bf(a.y), f2bf(a.z), f2bf(a.w),
                          f2bf(b.x), f2bf(b.y), f2bf(b.z), f2bf(b.w)};
  *(uint4*)(out + (size_t)i * 8) = *(uint4*)us;
}

// ---------------- GEMM: C[M,N] = A[M,K] * W[N,K]^T (both K-major bf16) -----
// m97 structure: 128x128 tile, BK=64, 4 waves (2x2), 4x4 16x16x32 frags,
// global_load_lds width-16 staging, 2 barriers per K-step.
template <int OUT_BF16>
__global__ __launch_bounds__(256) void gemm_bt(const unsigned short* __restrict__ A,
                                               const unsigned short* __restrict__ W,
                                               unsigned short* __restrict__ Ob,
                                               float* __restrict__ Of,
                                               int M, int N, int K) {
  __shared__ __align__(16) unsigned short As[128 * 64];
  __shared__ __align__(16) unsigned short Bs[128 * 64];
  const int m0 = blockIdx.x * 128, n0 = blockIdx.y * 128;
  const int tid = threadIdx.x, wid = tid >> 6, lane = tid & 63;
  const int wr = wid >> 1, wc = wid & 1;
  const int fr = lane & 15, fq = lane >> 4;
  f32x4 acc[4][4] = {};
  // staging: chunk c covers rows [c*8, c*8+8), lane l -> row c*8+(l>>3), col (l&7)*8
  const size_t Aoff = (size_t)(m0 + (lane >> 3)) * K + (lane & 7) * 8;
  const size_t Woff = (size_t)(n0 + (lane >> 3)) * K + (lane & 7) * 8;
  for (int k0 = 0; k0 < K; k0 += 64) {
#pragma unroll
    for (int i = 0; i < 4; ++i) {
      int c = wid * 4 + i;
      gload_lds16(A + Aoff + (size_t)(c * 8) * K + k0, &As[c * 512]);
      gload_lds16(W + Woff + (size_t)(c * 8) * K + k0, &Bs[c * 512]);
    }
    __syncthreads();   // drains vmcnt -> LDS tiles complete
#pragma unroll
    for (int kk = 0; kk < 2; ++kk) {
      i32x4 af[4], bw[4];
#pragma unroll
      for (int mi = 0; mi < 4; ++mi)
        af[mi] = *(const i32x4*)&As[(wr * 64 + mi * 16 + fr) * 64 + kk * 32 + fq * 8];
#pragma unroll
      for (int ni = 0; ni < 4; ++ni)
        bw[ni] = *(const i32x4*)&Bs[(wc * 64 + ni * 16 + fr) * 64 + kk * 32 + fq * 8];
#pragma unroll
      for (int mi = 0; mi < 4; ++mi)
#pragma unroll
        for (int ni = 0; ni < 4; ++ni) mfma16(af[mi], bw[ni], acc[mi][ni]);
    }
    __syncthreads();   // compute done before next-tile staging overwrites LDS
  }
  // epilogue: D(i,j): col = lane&15, row = (lane>>4)*4 + reg   [m89-verified]
#pragma unroll
  for (int mi = 0; mi < 4; ++mi)
#pragma unroll
    for (int ni = 0; ni < 4; ++ni) {
      int col = n0 + wc * 64 + ni * 16 + fr;
#pragma unroll
      for (int r = 0; r < 4; ++r) {
        int row = m0 + wr * 64 + mi * 16 + fq * 4 + r;
        if (OUT_BF16)
          Ob[(size_t)row * N + col] = f2bf(acc[mi][ni][r]);
        else
          Of[(size_t)row * N + col] = acc[mi][ni][r];
      }
    }
}

// ---------------- RoPE in-place on bf16 q/k (host-provided cos/sin) --------
__global__ __launch_bounds__(256) void rope_k(unsigned short* __restrict__ q,
                                              unsigned short* __restrict__ k,
                                              const float* __restrict__ cosb,
                                              const float* __restrict__ sinb) {
  unsigned short* t = blockIdx.y ? k : q;
  size_t idx = ((size_t)blockIdx.x * 256 + threadIdx.x) * 8;  // 4 (even,odd) pairs
  int s  = (int)((idx / D_) % S_);
  int d  = (int)(idx & (HD_ - 1));
  int i0 = d >> 1;
  unsigned short u[8];
  *(uint4*)u = *(const uint4*)&t[idx];
  float4 c  = *(const float4*)&cosb[s * (HD_ / 2) + i0];
  float4 sn = *(const float4*)&sinb[s * (HD_ / 2) + i0];
  float cs[4] = {c.x, c.y, c.z, c.w}, ss[4] = {sn.x, sn.y, sn.z, sn.w};
#pragma unroll
  for (int p = 0; p < 4; ++p) {
    float t0 = bf2f(u[2 * p]), t1 = bf2f(u[2 * p + 1]);
    u[2 * p]     = f2bf(t0 * cs[p] - t1 * ss[p]);
    u[2 * p + 1] = f2bf(t0 * ss[p] + t1 * cs[p]);
  }
  *(uint4*)&t[idx] = *(uint4*)u;
}

// ---------------- V transpose: (b,s,h,d) -> (b,h,d,s) ----------------------
__global__ __launch_bounds__(256) void transpose_v(const unsigned short* __restrict__ v,
                                                   unsigned short* __restrict__ vt) {
  __shared__ unsigned short tile[32][33];
  int s0 = blockIdx.x * 32, d0 = blockIdx.y * 32;
  int b = blockIdx.z / H_, h = blockIdx.z % H_;
  int tx = threadIdx.x & 31, ty = threadIdx.x >> 5;
#pragma unroll
  for (int r = 0; r < 32; r += 8)
    tile[ty + r][tx] = v[(size_t)(b * S_ + s0 + ty + r) * D_ + h * HD_ + d0 + tx];
  __syncthreads();
#pragma unroll
  for (int r = 0; r < 32; r += 8)
    vt[(size_t)((b * H_ + h) * HD_ + d0 + ty + r) * S_ + s0 + tx] = tile[tx][ty + r];
}

// ---------------- Flash attention: Q-tile 128, 8 waves x 16 q-rows ---------
__global__ __launch_bounds__(512) void flash_attn(const unsigned short* __restrict__ qb,
                                                  const unsigned short* __restrict__ kb,
                                                  const unsigned short* __restrict__ vtb,
                                                  unsigned short* __restrict__ ab) {
  __shared__ __align__(16) unsigned short Ks[64][136];   // keys x HD (+8 pad: 2-way banks)
  __shared__ __align__(16) unsigned short Vs[128][72];   // d x keys (+8 pad)
  __shared__ __align__(16) unsigned short Ps[8][16][72]; // per-wave P 16x64 (+8 pad)
  const int qt = blockIdx.x, h = blockIdx.y, b = blockIdx.z;
  const int tid = threadIdx.x, wid = tid >> 6, lane = tid & 63;
  const int fr = lane & 15, fq = lane >> 4;
  const int q0 = qt * 128 + wid * 16;
  i32x4 qf[4];
  {
    size_t base = (size_t)(b * S_ + q0 + fr) * D_ + h * HD_;
#pragma unroll
    for (int kk = 0; kk < 4; ++kk) qf[kk] = *(const i32x4*)&qb[base + kk * 32 + fq * 8];
  }
  f32x4 oacc[8] = {};
  float m_i[4] = {-1e30f, -1e30f, -1e30f, -1e30f};
  float l_i[4] = {0.f, 0.f, 0.f, 0.f};
  const float sc = 0.08838834764831845f;  // 1/sqrt(128)

  for (int k0 = 0; k0 < S_; k0 += 64) {
    __syncthreads();  // all waves done with previous K/V tiles
    for (int c = tid; c < 1024; c += 512) {
      int row = c >> 4, col = (c & 15) * 8;
      *(uint4*)&Ks[row][col] =
          *(const uint4*)&kb[(size_t)(b * S_ + k0 + row) * D_ + h * HD_ + col];
    }
    for (int c = tid; c < 1024; c += 512) {
      int row = c >> 3, col = (c & 7) * 8;
      *(uint4*)&Vs[row][col] =
          *(const uint4*)&vtb[(size_t)((b * H_ + h) * HD_ + row) * S_ + k0 + col];
    }
    __syncthreads();
    // S = Q K^T  (16 q-rows x 64 keys per wave)
    f32x4 sacc[4] = {};
#pragma unroll
    for (int nb = 0; nb < 4; ++nb)
#pragma unroll
      for (int kk = 0; kk < 4; ++kk)
        mfma16(qf[kk], *(const i32x4*)&Ks[nb * 16 + fr][kk * 32 + fq * 8], sacc[nb]);
    // online softmax; row = fq*4 + r, row-reduce across 16 lanes (fr)
#pragma unroll
    for (int r = 0; r < 4; ++r) {
      float s0 = sacc[0][r] * sc, s1 = sacc[1][r] * sc;
      float s2 = sacc[2][r] * sc, s3 = sacc[3][r] * sc;
      float mx = fmaxf(fmaxf(s0, s1), fmaxf(s2, s3));
#pragma unroll
      for (int o = 1; o < 16; o <<= 1) mx = fmaxf(mx, __shfl_xor(mx, o));
      float newm = fmaxf(m_i[r], mx);
      float fsc = __expf(m_i[r] - newm);
      m_i[r] = newm;
      float p0 = __expf(s0 - newm), p1 = __expf(s1 - newm);
      float p2 = __expf(s2 - newm), p3 = __expf(s3 - newm);
      float sum = p0 + p1 + p2 + p3;
#pragma unroll
      for (int o = 1; o < 16; o <<= 1) sum += __shfl_xor(sum, o);
      l_i[r] = l_i[r] * fsc + sum;
#pragma unroll
      for (int db = 0; db < 8; ++db) oacc[db][r] *= fsc;
      Ps[wid][fq * 4 + r][0 * 16 + fr] = f2bf(p0);
      Ps[wid][fq * 4 + r][1 * 16 + fr] = f2bf(p1);
      Ps[wid][fq * 4 + r][2 * 16 + fr] = f2bf(p2);
      Ps[wid][fq * 4 + r][3 * 16 + fr] = f2bf(p3);
    }
    // P re-fragment (wave-local LDS round-trip; DS ops in-order within a wave)
    i32x4 pf0 = *(const i32x4*)&Ps[wid][fr][fq * 8];
    i32x4 pf1 = *(const i32x4*)&Ps[wid][fr][32 + fq * 8];
#pragma unroll
    for (int db = 0; db < 8; ++db) {
      mfma16(pf0, *(const i32x4*)&Vs[db * 16 + fr][fq * 8], oacc[db]);
      mfma16(pf1, *(const i32x4*)&Vs[db * 16 + fr][32 + fq * 8], oacc[db]);
    }
  }
  // epilogue: normalize and store bf16 (b,s,h,d)
#pragma unroll
  for (int r = 0; r < 4; ++r) {
    float inv = 1.0f / l_i[r];
    size_t rowbase = (size_t)(b * S_ + q0 + fq * 4 + r) * D_ + h * HD_;
#pragma unroll
    for (int db = 0; db < 8; ++db)
      ab[rowbase + db * 16 + fr] = f2bf(oacc[db][r] * inv);
  }
}

// ---------------------------------------------------------------------------
extern "C" void kernel_launch(void* const* d_in, const int* in_sizes, int n_in,
                              void* d_out, int out_size, void* d_ws, size_t ws_size,
                              hipStream_t stream) {
  const float* x    = (const float*)d_in[0];
  const float* wq   = (const float*)d_in[1];
  const float* wk   = (const float*)d_in[2];
  const float* wv   = (const float*)d_in[3];
  const float* wo   = (const float*)d_in[4];
  const float* fcos = (const float*)d_in[7];
  const float* fsin = (const float*)d_in[8];
  float* out = (float*)d_out;

  unsigned short* xb  = (unsigned short*)d_ws;                 // T*D
  unsigned short* wqb = xb + (size_t)T_ * D_;                  // D*D each
  unsigned short* wkb = wqb + (size_t)D_ * D_;
  unsigned short* wvb = wkb + (size_t)D_ * D_;
  unsigned short* wob = wvb + (size_t)D_ * D_;
  unsigned short* qb  = wob + (size_t)D_ * D_;                 // T*D each
  unsigned short* kb  = qb + (size_t)T_ * D_;
  unsigned short* vb  = kb + (size_t)T_ * D_;
  unsigned short* vtb = vb + (size_t)T_ * D_;
  unsigned short* ab  = vtb + (size_t)T_ * D_;
  // total ws use: 16MB + 4*32MB + 5*16MB = 224MB

  cvt_bf16<<<T_ * D_ / 8 / 256, 256, 0, stream>>>(x, xb, T_ * D_ / 8);
  cvt_bf16<<<D_ * D_ / 8 / 256, 256, 0, stream>>>(wq, wqb, D_ * D_ / 8);
  cvt_bf16<<<D_ * D_ / 8 / 256, 256, 0, stream>>>(wk, wkb, D_ * D_ / 8);
  cvt_bf16<<<D_ * D_ / 8 / 256, 256, 0, stream>>>(wv, wvb, D_ * D_ / 8);
  cvt_bf16<<<D_ * D_ / 8 / 256, 256, 0, stream>>>(wo, wob, D_ * D_ / 8);

  dim3 gg(T_ / 128, D_ / 128);
  gemm_bt<1><<<gg, 256, 0, stream>>>(xb, wqb, qb, nullptr, T_, D_, D_);
  gemm_bt<1><<<gg, 256, 0, stream>>>(xb, wkb, kb, nullptr, T_, D_, D_);
  gemm_bt<1><<<gg, 256, 0, stream>>>(xb, wvb, vb, nullptr, T_, D_, D_);

  rope_k<<<dim3(T_ * D_ / 8 / 256, 2), 256, 0, stream>>>(qb, kb, fcos, fsin);
  transpose_v<<<dim3(S_ / 32, HD_ / 32, B_ * H_), 256, 0, stream>>>(vb, vtb);
  flash_attn<<<dim3(S_ / 128, H_, B_), 512, 0, stream>>>(qb, kb, vtb, ab);

  gemm_bt<0><<<gg, 256, 0, stream>>>(ab, wob, nullptr, out, T_, D_, D_);
}

// Round 2
// 590.335 us; speedup vs baseline: 1.0272x; 1.0272x over previous
//
#include <hip/hip_runtime.h>

#define B_  2
#define S_  1024
#define D_  4096
#define H_  32
#define HD_ 128
#define T_  (B_*S_)   // 2048 tokens

typedef int   i32x4 __attribute__((ext_vector_type(4)));
typedef float f32x4 __attribute__((ext_vector_type(4)));
typedef unsigned short u16;

__device__ __forceinline__ u16 f2bf(float f) {
  unsigned int u = __float_as_uint(f);
  u += 0x7fffu + ((u >> 16) & 1u);     // round-to-nearest-even
  return (u16)(u >> 16);
}
__device__ __forceinline__ float bf2f(u16 h) {
  return __uint_as_float(((unsigned int)h) << 16);
}
__device__ __forceinline__ void gload_lds16(const void* g, void* l) {
  __builtin_amdgcn_global_load_lds(
      (const __attribute__((address_space(1))) unsigned int*)g,
      (__attribute__((address_space(3))) unsigned int*)l, 16, 0, 0);
}
__device__ __forceinline__ void mfma16(i32x4 a, i32x4 b, f32x4& c) {
  asm("v_mfma_f32_16x16x32_bf16 %0, %1, %2, %0" : "+v"(c) : "v"(a), "v"(b));
}

// ---------------- f32 -> bf16 convert (vectorized, 8 elem/thread) ----------
__global__ __launch_bounds__(256) void cvt_bf16(const float* __restrict__ in,
                                                u16* __restrict__ out, int n8) {
  int i = blockIdx.x * 256 + threadIdx.x;
  if (i >= n8) return;
  const float4* p = (const float4*)in + (size_t)i * 2;
  float4 a = p[0], b = p[1];
  u16 us[8] = {f2bf(a.x), f2bf(a.y), f2bf(a.z), f2bf(a.w),
               f2bf(b.x), f2bf(b.y), f2bf(b.z), f2bf(b.w)};
  *(uint4*)(out + (size_t)i * 8) = *(uint4*)us;
}

// ---- stage one 128x64 bf16 half-tile: linear LDS dest, pre-swizzled source
// lane k of wave w, load l -> LDS byte (w*2+l)*1024 + k*16  (rows of 128B)
// read-side XOR: stored slot16 s holds logical col16 s^(row&7)
__device__ __forceinline__ void stage_half(const u16* __restrict__ g, int ldk,
                                           int row0, int k0, u16* lds,
                                           int wid, int lane) {
  const int rsub = lane >> 3;
  const int c16  = (lane & 7) ^ rsub;
#pragma unroll
  for (int l = 0; l < 2; ++l) {
    const int r = (wid * 2 + l) * 8 + rsub;
    gload_lds16(g + (size_t)(row0 + r) * ldk + k0 + c16 * 8,
                lds + (wid * 2 + l) * 512);
  }
}

// ---------------- 256x256 8-phase GEMM (T1+T2+T3+T4+T5), C = A * W^T -------
// QKV=1: scatter bf16 into 3 buffers of N=4096 by column block.
// QKV=0: write f32 into Of (N = NB*256).
template <int QKV>
__global__ __launch_bounds__(512, 2) void gemm8(const u16* __restrict__ A,
                                                const u16* __restrict__ W,
                                                u16* __restrict__ O0,
                                                u16* __restrict__ O1,
                                                u16* __restrict__ O2,
                                                float* __restrict__ Of,
                                                int MB, int NB, int K) {
  __shared__ __align__(16) u16 LA[2][2][128 * 64];  // slot, half, row*64+col
  __shared__ __align__(16) u16 LB[2][2][128 * 64];
  const int nwg = MB * NB;                 // both grids are %8==0
  const int cpx = nwg >> 3;
  const int bid = blockIdx.x;
  const int swz = (bid & 7) * cpx + (bid >> 3);   // T1: XCD chunk
  const int bm = swz % MB, bn = swz / MB;         // M-fastest: 2D chunk/XCD
  const int m0 = bm * 256, n0 = bn * 256;
  const int tid = threadIdx.x, wid = tid >> 6, lane = tid & 63;
  const int wr = wid >> 2, wc = wid & 3;          // 2x4 wave grid
  const int fr = lane & 15, fq = lane >> 4;
  const int nkt = K >> 6;
  f32x4 acc[8][4] = {};

  // half-tile stream: g = tile*4 + part, parts = {B0,B1,A0,A1}
  auto STAGE = [&](int gidx) {
    if (gidx >= 4 * nkt) return;
    const int t = gidx >> 2, part = gidx & 3, slot = t & 1, k0 = t * 64;
    if (part < 2)
      stage_half(W, K, n0 + part * 128, k0, &LB[slot][part][0], wid, lane);
    else
      stage_half(A, K, m0 + (part - 2) * 128, k0, &LA[slot][part - 2][0], wid, lane);
  };

  // prologue: tile0 complete + tile1 B halves; wait tile0 landed (8 of 12 instr)
  for (int g = 0; g < 6; ++g) STAGE(g);
  asm volatile("s_waitcnt vmcnt(4)" ::: "memory");
  __builtin_amdgcn_s_barrier();

  for (int t = 0; t < nkt; ++t) {
    const int slot = t & 1;
    i32x4 bfr[4][2];
#pragma unroll
    for (int q = 0; q < 4; ++q) {
      // ds-load this phase's A quadrant (4 x ds_read_b128), swizzled
      i32x4 af[2][2];
#pragma unroll
      for (int i = 0; i < 2; ++i)
#pragma unroll
        for (int kk = 0; kk < 2; ++kk) {
          const int r = (q * 2 + i) * 16 + fr;
          const int s16 = (kk * 4 + fq) ^ (r & 7);
          af[i][kk] = *(const i32x4*)&LA[slot][wr][r * 64 + s16 * 8];
        }
      if (q == 0) {  // all B frags for this K-tile (8 x ds_read_b128)
#pragma unroll
        for (int ni = 0; ni < 4; ++ni)
#pragma unroll
          for (int kk = 0; kk < 2; ++kk) {
            const int rr = (wc & 1) * 64 + ni * 16 + fr;
            const int s16 = (kk * 4 + fq) ^ (rr & 7);
            bfr[ni][kk] = *(const i32x4*)&LB[slot][wc >> 1][rr * 64 + s16 * 8];
          }
      }
      // stage lag: q0->t+1:A0, q1->t+1:A1, q2->t+2:B0, q3->t+2:B1
      // (current-slot B overwrite is post-phase-0-barrier => WAR-safe)
      STAGE(4 * t + 6 + q);
      if (q == 3) {  // counted vmcnt once per K-tile: tile t+1 fully landed
        if (t < nkt - 2) asm volatile("s_waitcnt vmcnt(4)" ::: "memory");
        else             asm volatile("s_waitcnt vmcnt(0)" ::: "memory");
      }
      __builtin_amdgcn_s_barrier();
      asm volatile("s_waitcnt lgkmcnt(0)" ::: "memory");
      __builtin_amdgcn_sched_barrier(0);
      __builtin_amdgcn_s_setprio(1);
#pragma unroll
      for (int i = 0; i < 2; ++i)
#pragma unroll
        for (int ni = 0; ni < 4; ++ni)
#pragma unroll
          for (int kk = 0; kk < 2; ++kk)
            mfma16(af[i][kk], bfr[ni][kk], acc[q * 2 + i][ni]);
      __builtin_amdgcn_s_setprio(0);
      __builtin_amdgcn_s_barrier();
    }
  }

  // epilogue: D(i,j): col = lane&15, row = (lane>>4)*4 + reg
  if (QKV) {
    u16* Ob = (n0 < 4096) ? O0 : (n0 < 8192 ? O1 : O2);
    const int nc = n0 & 4095;
#pragma unroll
    for (int mi = 0; mi < 8; ++mi)
#pragma unroll
      for (int ni = 0; ni < 4; ++ni) {
        const int col = nc + wc * 64 + ni * 16 + fr;
#pragma unroll
        for (int r = 0; r < 4; ++r) {
          const int row = m0 + wr * 128 + mi * 16 + fq * 4 + r;
          Ob[(size_t)row * 4096 + col] = f2bf(acc[mi][ni][r]);
        }
      }
  } else {
    const int Nn = NB * 256;
#pragma unroll
    for (int mi = 0; mi < 8; ++mi)
#pragma unroll
      for (int ni = 0; ni < 4; ++ni) {
        const int col = n0 + wc * 64 + ni * 16 + fr;
#pragma unroll
        for (int r = 0; r < 4; ++r) {
          const int row = m0 + wr * 128 + mi * 16 + fq * 4 + r;
          Of[(size_t)row * Nn + col] = acc[mi][ni][r];
        }
      }
  }
}

// ---------------- RoPE in-place on bf16 q/k (host-provided cos/sin) --------
__global__ __launch_bounds__(256) void rope_k(u16* __restrict__ q,
                                              u16* __restrict__ k,
                                              const float* __restrict__ cosb,
                                              const float* __restrict__ sinb) {
  u16* t = blockIdx.y ? k : q;
  size_t idx = ((size_t)blockIdx.x * 256 + threadIdx.x) * 8;
  int s  = (int)((idx / D_) % S_);
  int d  = (int)(idx & (HD_ - 1));
  int i0 = d >> 1;
  u16 u[8];
  *(uint4*)u = *(const uint4*)&t[idx];
  float4 c  = *(const float4*)&cosb[s * (HD_ / 2) + i0];
  float4 sn = *(const float4*)&sinb[s * (HD_ / 2) + i0];
  float cs[4] = {c.x, c.y, c.z, c.w}, ss[4] = {sn.x, sn.y, sn.z, sn.w};
#pragma unroll
  for (int p = 0; p < 4; ++p) {
    float t0 = bf2f(u[2 * p]), t1 = bf2f(u[2 * p + 1]);
    u[2 * p]     = f2bf(t0 * cs[p] - t1 * ss[p]);
    u[2 * p + 1] = f2bf(t0 * ss[p] + t1 * cs[p]);
  }
  *(uint4*)&t[idx] = *(uint4*)u;
}

// ---------------- V transpose: (b,s,h,d) -> (b,h,d,s) ----------------------
__global__ __launch_bounds__(256) void transpose_v(const u16* __restrict__ v,
                                                   u16* __restrict__ vt) {
  __shared__ u16 tile[32][33];
  int s0 = blockIdx.x * 32, d0 = blockIdx.y * 32;
  int b = blockIdx.z / H_, h = blockIdx.z % H_;
  int tx = threadIdx.x & 31, ty = threadIdx.x >> 5;
#pragma unroll
  for (int r = 0; r < 32; r += 8)
    tile[ty + r][tx] = v[(size_t)(b * S_ + s0 + ty + r) * D_ + h * HD_ + d0 + tx];
  __syncthreads();
#pragma unroll
  for (int r = 0; r < 32; r += 8)
    vt[(size_t)((b * H_ + h) * HD_ + d0 + ty + r) * S_ + s0 + tx] = tile[tx][ty + r];
}

// ---------------- Flash attention: Q-tile 128, 8 waves x 16 q-rows ---------
__global__ __launch_bounds__(512) void flash_attn(const u16* __restrict__ qb,
                                                  const u16* __restrict__ kb,
                                                  const u16* __restrict__ vtb,
                                                  u16* __restrict__ ab) {
  __shared__ __align__(16) u16 Ks[64][136];
  __shared__ __align__(16) u16 Vs[128][72];
  __shared__ __align__(16) u16 Ps[8][16][72];
  const int qt = blockIdx.x, h = blockIdx.y, b = blockIdx.z;
  const int tid = threadIdx.x, wid = tid >> 6, lane = tid & 63;
  const int fr = lane & 15, fq = lane >> 4;
  const int q0 = qt * 128 + wid * 16;
  i32x4 qf[4];
  {
    size_t base = (size_t)(b * S_ + q0 + fr) * D_ + h * HD_;
#pragma unroll
    for (int kk = 0; kk < 4; ++kk) qf[kk] = *(const i32x4*)&qb[base + kk * 32 + fq * 8];
  }
  f32x4 oacc[8] = {};
  float m_i[4] = {-1e30f, -1e30f, -1e30f, -1e30f};
  float l_i[4] = {0.f, 0.f, 0.f, 0.f};
  const float sc = 0.08838834764831845f;  // 1/sqrt(128)

  for (int k0 = 0; k0 < S_; k0 += 64) {
    __syncthreads();
    for (int c = tid; c < 1024; c += 512) {
      int row = c >> 4, col = (c & 15) * 8;
      *(uint4*)&Ks[row][col] =
          *(const uint4*)&kb[(size_t)(b * S_ + k0 + row) * D_ + h * HD_ + col];
    }
    for (int c = tid; c < 1024; c += 512) {
      int row = c >> 3, col = (c & 7) * 8;
      *(uint4*)&Vs[row][col] =
          *(const uint4*)&vtb[(size_t)((b * H_ + h) * HD_ + row) * S_ + k0 + col];
    }
    __syncthreads();
    f32x4 sacc[4] = {};
#pragma unroll
    for (int nb = 0; nb < 4; ++nb)
#pragma unroll
      for (int kk = 0; kk < 4; ++kk)
        mfma16(qf[kk], *(const i32x4*)&Ks[nb * 16 + fr][kk * 32 + fq * 8], sacc[nb]);
#pragma unroll
    for (int r = 0; r < 4; ++r) {
      float s0 = sacc[0][r] * sc, s1 = sacc[1][r] * sc;
      float s2 = sacc[2][r] * sc, s3 = sacc[3][r] * sc;
      float mx = fmaxf(fmaxf(s0, s1), fmaxf(s2, s3));
#pragma unroll
      for (int o = 1; o < 16; o <<= 1) mx = fmaxf(mx, __shfl_xor(mx, o));
      float newm = fmaxf(m_i[r], mx);
      float fsc = __expf(m_i[r] - newm);
      m_i[r] = newm;
      float p0 = __expf(s0 - newm), p1 = __expf(s1 - newm);
      float p2 = __expf(s2 - newm), p3 = __expf(s3 - newm);
      float sum = p0 + p1 + p2 + p3;
#pragma unroll
      for (int o = 1; o < 16; o <<= 1) sum += __shfl_xor(sum, o);
      l_i[r] = l_i[r] * fsc + sum;
#pragma unroll
      for (int db = 0; db < 8; ++db) oacc[db][r] *= fsc;
      Ps[wid][fq * 4 + r][0 * 16 + fr] = f2bf(p0);
      Ps[wid][fq * 4 + r][1 * 16 + fr] = f2bf(p1);
      Ps[wid][fq * 4 + r][2 * 16 + fr] = f2bf(p2);
      Ps[wid][fq * 4 + r][3 * 16 + fr] = f2bf(p3);
    }
    i32x4 pf0 = *(const i32x4*)&Ps[wid][fr][fq * 8];
    i32x4 pf1 = *(const i32x4*)&Ps[wid][fr][32 + fq * 8];
#pragma unroll
    for (int db = 0; db < 8; ++db) {
      mfma16(pf0, *(const i32x4*)&Vs[db * 16 + fr][fq * 8], oacc[db]);
      mfma16(pf1, *(const i32x4*)&Vs[db * 16 + fr][32 + fq * 8], oacc[db]);
    }
  }
#pragma unroll
  for (int r = 0; r < 4; ++r) {
    float inv = 1.0f / l_i[r];
    size_t rowbase = (size_t)(b * S_ + q0 + fq * 4 + r) * D_ + h * HD_;
#pragma unroll
    for (int db = 0; db < 8; ++db)
      ab[rowbase + db * 16 + fr] = f2bf(oacc[db][r] * inv);
  }
}

// ---------------------------------------------------------------------------
extern "C" void kernel_launch(void* const* d_in, const int* in_sizes, int n_in,
                              void* d_out, int out_size, void* d_ws, size_t ws_size,
                              hipStream_t stream) {
  const float* x    = (const float*)d_in[0];
  const float* wq   = (const float*)d_in[1];
  const float* wk   = (const float*)d_in[2];
  const float* wv   = (const float*)d_in[3];
  const float* wo   = (const float*)d_in[4];
  const float* fcos = (const float*)d_in[7];
  const float* fsin = (const float*)d_in[8];
  float* out = (float*)d_out;

  u16* xb  = (u16*)d_ws;                      // T*D
  u16* wqb = xb + (size_t)T_ * D_;            // D*D each; wq|wk|wv CONTIGUOUS
  u16* wkb = wqb + (size_t)D_ * D_;
  u16* wvb = wkb + (size_t)D_ * D_;
  u16* wob = wvb + (size_t)D_ * D_;
  u16* qb  = wob + (size_t)D_ * D_;           // T*D each
  u16* kb  = qb + (size_t)T_ * D_;
  u16* vb  = kb + (size_t)T_ * D_;
  u16* vtb = vb + (size_t)T_ * D_;
  u16* ab  = vtb + (size_t)T_ * D_;

  cvt_bf16<<<T_ * D_ / 8 / 256, 256, 0, stream>>>(x, xb, T_ * D_ / 8);
  cvt_bf16<<<D_ * D_ / 8 / 256, 256, 0, stream>>>(wq, wqb, D_ * D_ / 8);
  cvt_bf16<<<D_ * D_ / 8 / 256, 256, 0, stream>>>(wk, wkb, D_ * D_ / 8);
  cvt_bf16<<<D_ * D_ / 8 / 256, 256, 0, stream>>>(wv, wvb, D_ * D_ / 8);
  cvt_bf16<<<D_ * D_ / 8 / 256, 256, 0, stream>>>(wo, wob, D_ * D_ / 8);

  // fused QKV: M=2048, N=12288 (wq|wk|wv), K=4096 -> 384 blocks (1.5/CU)
  gemm8<1><<<8 * 48, 512, 0, stream>>>(xb, wqb, qb, kb, vb, nullptr, 8, 48, D_);

  rope_k<<<dim3(T_ * D_ / 8 / 256, 2), 256, 0, stream>>>(qb, kb, fcos, fsin);
  transpose_v<<<dim3(S_ / 32, HD_ / 32, B_ * H_), 256, 0, stream>>>(vb, vtb);
  flash_attn<<<dim3(S_ / 128, H_, B_), 512, 0, stream>>>(qb, kb, vtb, ab);

  // output projection: M=2048, N=4096 -> 128 blocks
  gemm8<0><<<8 * 16, 512, 0, stream>>>(ab, wob, nullptr, nullptr, nullptr, out, 8, 16, D_);
}